// Round 10
// baseline (282.612 us; speedup 1.0000x reference)
//
#include <hip/hip_runtime.h>
#include <math.h>

#define T_STEPS 20
#define LOG2E 1.44269504088896f

typedef _Float16 half8 __attribute__((ext_vector_type(8)));
typedef __fp16 fp16x2 __attribute__((ext_vector_type(2)));
typedef float f32x4 __attribute__((ext_vector_type(4)));

// native v_exp_f32 = 2^x (gate weights pre-scaled by +-log2e so no mul)
__device__ __forceinline__ float exp2_f(float v) {
  float r; asm("v_exp_f32 %0, %1" : "=v"(r) : "v"(v)); return r;
}
// helpers for cell tanh + classifier head
__device__ __forceinline__ float sigm(float v) {
  return __builtin_amdgcn_rcpf(1.0f + __expf(-v));
}
__device__ __forceinline__ float tanh_f(float v) {
  return 1.0f - 2.0f * __builtin_amdgcn_rcpf(1.0f + __expf(2.0f * v));
}

// lgkm-only workgroup barrier (R1: neutral vs __syncthreads, never worse;
// lets global prefetch ride across barriers).
__device__ __forceinline__ void barrier_lgkm() {
  asm volatile("s_waitcnt lgkmcnt(0)" ::: "memory");
  __builtin_amdgcn_s_barrier();
  asm volatile("" ::: "memory");
}

// pack f32x4 -> 4 f16 (RTZ) as int2 for ds_write_b64
__device__ __forceinline__ int2 pkpair(const f32x4 D) {
  const fp16x2 p0 = __builtin_amdgcn_cvt_pkrtz(D[0], D[1]);
  const fp16x2 p1 = __builtin_amdgcn_cvt_pkrtz(D[2], D[3]);
  int2 r;
  r.x = __builtin_bit_cast(int, p0);
  r.y = __builtin_bit_cast(int, p1);
  return r;
}

// R13 = R12 + __launch_bounds__(1024, 4). R9 post-mortem: R12's hoisted
// loop-invariants exceeded the 64-VGPR cap that __launch_bounds__(1024)
// implies (compiler targeted 8 waves/SIMD = 2 blocks/CU, which NEVER
// happens for this 16-wave/80KB-LDS block) -> 53 MB/dispatch scratch
// spill traffic (WRITE_SIZE 32KB->26.6MB), dur 70->140us. Declaring
// 4 waves/EU (the true residency) raises the cap to 128 VGPRs: hoists
// live in registers, zero occupancy change.
// Carried from R12 (content unchanged):
//  - P1 loop-invariant LDS reads hoisted to regs (t==0 keeps LDS path).
//  - 3a: vectorized mask loads; trunc-cast bins, upper clamp only.
//  - gate weights pre-scaled by -log2e / +2log2e -> raw v_exp_f32 nonlin.
// MFMA layouts (verified m89 + R7): A[m=lane&15][k=quad*8+j] row-major
// [m][k]; B[k][n=lane&15] row-major [n][k]; D row=4*quad+reg, col=lane&15.
__global__ __launch_bounds__(1024, 4)
void traj_disc(const float* __restrict__ x, const float* __restrict__ dmat,
               const float* __restrict__ bmat, const float* __restrict__ hmat,
               const float* __restrict__ maskp,
               const float* __restrict__ embW, const float* __restrict__ embb,
               const float* __restrict__ Wih, const float* __restrict__ Whh,
               const float* __restrict__ bih, const float* __restrict__ bhh,
               const float* __restrict__ dom,
               const float* __restrict__ e2aW, const float* __restrict__ e2ab,
               const float* __restrict__ spaW, const float* __restrict__ spab,
               const float* __restrict__ a2eW, const float* __restrict__ a2eb,
               const float* __restrict__ clsW, const float* __restrict__ clsb,
               const float* __restrict__ h0p, const float* __restrict__ c0p,
               float* __restrict__ out)
{
  // f16 pitches 40/72 halves (80/144 B: 16B-aligned, <=2-way banks).
  __shared__ __align__(16) _Float16 sgw[128*40];   // Whh*s_q        (t=0 path)
  __shared__ __align__(16) _Float16 sgwc[128*40];  // (Whh@a2eW)*s_q (t>0 path)
  __shared__ __align__(16) float4   sgmb[128];     // (M0,M1,b_t0,b_tn)*s_q
  __shared__ __align__(16) _Float16 sESaT[32*40];  // (e2aW^T@spaW_a)^T[zk][h]
  __shared__ __align__(16) _Float16 sEStT[32*40];  // (e2aW^T@spaW_t)^T[zk][h]
  __shared__ float bz[32];                          // folded z bias
  __shared__ float sdom[144];
  __shared__ float sm[1280];                        // mask[b] as [t][n]
  __shared__ float sclsc[32];                       // clsW@a2eW fold
  __shared__ float sclsb2[1];
  __shared__ __align__(16) _Float16 sH[64*40];     // h_lstm rows f16
  __shared__ __align__(16) _Float16 swA[64*72];    // normalized w, double-buffered
  __shared__ __align__(16) _Float16 swB[64*72];
  __shared__ __align__(16) _Float16 sz_[64*40];    // Z rows f16 (recurrent state; h0 at t=0)
  __shared__ __align__(16) _Float16 sqb[8*16*72];  // per-wave Q^T scratch

  const int tid = threadIdx.x;
  const int b = blockIdx.x;
  const int w = tid >> 6;     // wave 0..15
  const int l = tid & 63;
  const int quad = l >> 4;
  const int n16 = l & 15;
  const int i8 = (tid >= 512) ? ((tid - 512) >> 3) : 0;  // 3a node (waves 8-15)
  const int s8 = tid & 7;                                 // 3a j-block

  // ---- one-time staging ----
  for (int idx = tid; idx < 4096; idx += 1024) {
    const int g = idx >> 5;
    const float sq = ((g >> 5) == 2) ? 2.0f*LOG2E : -LOG2E;
    sgw[g*40 + (idx & 31)] = (_Float16)(Whh[idx] * sq);
  }
  {  // Wcomb[g][k] = sum_h Whh[g][h]*a2eW[h][k], then *s_q
    const int g = tid >> 3, kb = (tid & 7) << 2;
    const float sq = ((g >> 5) == 2) ? 2.0f*LOG2E : -LOG2E;
    float a0 = 0.f, a1 = 0.f, a2 = 0.f, a3 = 0.f;
    #pragma unroll
    for (int h = 0; h < 32; ++h) {
      const float wv = Whh[g*32 + h];
      a0 = fmaf(wv, a2eW[h*32 + kb + 0], a0);
      a1 = fmaf(wv, a2eW[h*32 + kb + 1], a1);
      a2 = fmaf(wv, a2eW[h*32 + kb + 2], a2);
      a3 = fmaf(wv, a2eW[h*32 + kb + 3], a3);
    }
    sgwc[g*40 + kb + 0] = (_Float16)(a0*sq); sgwc[g*40 + kb + 1] = (_Float16)(a1*sq);
    sgwc[g*40 + kb + 2] = (_Float16)(a2*sq); sgwc[g*40 + kb + 3] = (_Float16)(a3*sq);
  }
  if (tid < 128) {  // x-projection fold + both bias variants, *s_q
    const float sq = ((tid >> 5) == 2) ? 2.0f*LOG2E : -LOG2E;
    float m0 = 0.f, m1 = 0.f, b0 = bih[tid] + bhh[tid];
    #pragma unroll
    for (int e = 0; e < 16; ++e) {
      float wv_ = Wih[tid*16 + e];
      m0 = fmaf(wv_, embW[2*e],   m0);
      m1 = fmaf(wv_, embW[2*e+1], m1);
      b0 = fmaf(wv_, embb[e],     b0);
    }
    float bn = b0;
    #pragma unroll
    for (int h = 0; h < 32; ++h) bn = fmaf(Whh[tid*32 + h], a2eb[h], bn);
    sgmb[tid] = make_float4(m0*sq, m1*sq, b0*sq, bn*sq);
  }
  {  // ESa^T / ESt^T
    const int zk = tid >> 5, hc = tid & 31;
    float sa_ = 0.f, st_ = 0.f;
    #pragma unroll
    for (int a = 0; a < 32; ++a) {
      const float ev = e2aW[a*32 + hc];
      sa_ = fmaf(spaW[zk*64 + a],      ev, sa_);
      st_ = fmaf(spaW[zk*64 + 32 + a], ev, st_);
    }
    sESaT[zk*40 + hc] = (_Float16)sa_;
    sEStT[zk*40 + hc] = (_Float16)st_;
  }
  if (tid < 32) {  // bz fold + classifier fold
    float acc = spab[tid];
    #pragma unroll
    for (int a = 0; a < 32; ++a)
      acc = fmaf(e2ab[a], spaW[tid*64 + a] + spaW[tid*64 + 32 + a], acc);
    bz[tid] = acc;
    float cc = 0.f;
    #pragma unroll
    for (int h = 0; h < 32; ++h) cc = fmaf(clsW[h], a2eW[h*32 + tid], cc);
    sclsc[tid] = cc;
  }
  if (tid == 0) {
    float cb = clsb[0];
    #pragma unroll
    for (int h = 0; h < 32; ++h) cb = fmaf(clsW[h], a2eb[h], cb);
    sclsb2[0] = cb;
  }
  if (tid < 144) sdom[tid] = dom[tid];
  // mask as [t][n]
  for (int idx = tid; idx < 1280; idx += 1024)
    sm[idx] = maskp[(size_t)b*1280 + (size_t)(idx & 63)*20 + (idx >> 6)];
  // h0 -> sz_ (t=0 op1 reads sz_; sH is written fresh every step in P1)
  for (int idx = tid; idx < 2048; idx += 1024) sz_[(idx >> 5)*40 + (idx & 31)] = (_Float16)h0p[(size_t)b*2048 + idx];

  // per-path persistent registers
  f32x4 ccell;
  float2 xA, xB, xC, xD;
  f32x4 dmv0, dmv1, bmv0, bmv1, hmv0, hmv1;
  const float* xpre = nullptr;
  size_t ebp = 0;
  const int r = w >> 1, c = w & 1;   // waves 0-7: tile (node-block r, col-block c)
  if (w < 8) {
    const int hh = 16*c + n16;
    #pragma unroll
    for (int reg = 0; reg < 4; ++reg)
      ccell[reg] = c0p[(size_t)b*2048 + (size_t)(16*r + 4*quad + reg)*32 + hh];
    xpre = x + (size_t)(b*64 + 16*r + 4*quad) * 40;
    xA = *(const float2*)(xpre +   0);
    xB = *(const float2*)(xpre +  40);
    xC = *(const float2*)(xpre +  80);
    xD = *(const float2*)(xpre + 120);
  } else {
    ebp = ((size_t)(b*64 + i8)*20)*64 + (size_t)(s8*8);   // edges t=0
    dmv0 = *(const f32x4*)(dmat + ebp); dmv1 = *(const f32x4*)(dmat + ebp + 4);
    bmv0 = *(const f32x4*)(bmat + ebp); bmv1 = *(const f32x4*)(bmat + ebp + 4);
    hmv0 = *(const f32x4*)(hmat + ebp); hmv1 = *(const f32x4*)(hmat + ebp + 4);
  }
  __syncthreads();

  // bins: bm,hm in [0,360) -> trunc == floor; upper clamp = rounding insurance
#define WC(dst, k, dmv, bmv, hmv, mrv, jof) { \
  int ib_ = (int)(bmv[k] * (1.0f/30.0f)); ib_ = ib_ > 11 ? 11 : ib_; \
  int ih_ = (int)(hmv[k] * (1.0f/30.0f)); ih_ = ih_ > 11 ? 11 : ih_; \
  float w_ = fmaxf(sdom[ib_*12 + ih_] - dmv[k], 0.0f) * (mi_ * mrv[k]); \
  w_ = (8*s8 + (jof) == i8) ? 0.0f : w_; dst[k] = w_; rs += w_; }

#define DO_3A(tn_, swdst) { \
  const int tloc = (tn_); \
  const float mi_ = sm[tloc*64 + i8]; \
  const f32x4 mr0 = *(const f32x4*)(sm + tloc*64 + 8*s8); \
  const f32x4 mr1 = *(const f32x4*)(sm + tloc*64 + 8*s8 + 4); \
  f32x4 wnA, wnB; float rs = 0.0f; \
  WC(wnA,0,dmv0,bmv0,hmv0,mr0,0) WC(wnA,1,dmv0,bmv0,hmv0,mr0,1) \
  WC(wnA,2,dmv0,bmv0,hmv0,mr0,2) WC(wnA,3,dmv0,bmv0,hmv0,mr0,3) \
  WC(wnB,0,dmv1,bmv1,hmv1,mr1,4) WC(wnB,1,dmv1,bmv1,hmv1,mr1,5) \
  WC(wnB,2,dmv1,bmv1,hmv1,mr1,6) WC(wnB,3,dmv1,bmv1,hmv1,mr1,7) \
  rs += __shfl_xor(rs, 1); rs += __shfl_xor(rs, 2); rs += __shfl_xor(rs, 4); \
  const float inv_ = __builtin_amdgcn_rcpf(rs + 1e-12f); \
  half8 hw; \
  hw[0] = (_Float16)(wnA[0]*inv_); hw[1] = (_Float16)(wnA[1]*inv_); \
  hw[2] = (_Float16)(wnA[2]*inv_); hw[3] = (_Float16)(wnA[3]*inv_); \
  hw[4] = (_Float16)(wnB[0]*inv_); hw[5] = (_Float16)(wnB[1]*inv_); \
  hw[6] = (_Float16)(wnB[2]*inv_); hw[7] = (_Float16)(wnB[3]*inv_); \
  *(half8*)((swdst) + i8*72 + s8*8) = hw; }

  // loop-invariant register hoists (live in regs under the 128-VGPR cap)
  half8 EStB{}, ESaB{};
  float bzv = 0.f;
  half8 Bc0{}, Bc1{}, Bc2{}, Bc3{};      // sgwc B-fragments (t>0 path)
  float2 mxq0{}, mxq1{}, mxq2{}, mxq3{}; // (M0,M1) per gate-col tile
  float mbn0 = 0.f, mbn1 = 0.f, mbn2 = 0.f, mbn3 = 0.f;  // folded bias (t>0)
  if (w < 8) {
    EStB = *(const half8*)(sEStT + (16*c + n16)*40 + quad*8);
    ESaB = *(const half8*)(sESaT + (16*c + n16)*40 + quad*8);
    bzv = bz[16*c + n16];
    Bc0 = *(const half8*)(sgwc + (16*(c    ) + n16)*40 + quad*8);
    Bc1 = *(const half8*)(sgwc + (16*(2 + c) + n16)*40 + quad*8);
    Bc2 = *(const half8*)(sgwc + (16*(4 + c) + n16)*40 + quad*8);
    Bc3 = *(const half8*)(sgwc + (16*(6 + c) + n16)*40 + quad*8);
    const float4 t0 = sgmb[16*(c    ) + n16]; mxq0 = make_float2(t0.x, t0.y); mbn0 = t0.w;
    const float4 t1 = sgmb[16*(2 + c) + n16]; mxq1 = make_float2(t1.x, t1.y); mbn1 = t1.w;
    const float4 t2 = sgmb[16*(4 + c) + n16]; mxq2 = make_float2(t2.x, t2.y); mbn2 = t2.w;
    const float4 t3 = sgmb[16*(6 + c) + n16]; mxq3 = make_float2(t3.x, t3.y); mbn3 = t3.w;
  } else {
    DO_3A(0, swA);
    const size_t eb1 = ebp + 64;
    dmv0 = *(const f32x4*)(dmat + eb1); dmv1 = *(const f32x4*)(dmat + eb1 + 4);
    bmv0 = *(const f32x4*)(bmat + eb1); bmv1 = *(const f32x4*)(bmat + eb1 + 4);
    hmv0 = *(const f32x4*)(hmat + eb1); hmv1 = *(const f32x4*)(hmat + eb1 + 4);
  }

#define OP1R(Gq, Bfv, mxv, mbv) { \
  f32x4 Cv; \
  Cv[0] = fmaf(xA.x, mxv.x, fmaf(xA.y, mxv.y, mbv)); \
  Cv[1] = fmaf(xB.x, mxv.x, fmaf(xB.y, mxv.y, mbv)); \
  Cv[2] = fmaf(xC.x, mxv.x, fmaf(xC.y, mxv.y, mbv)); \
  Cv[3] = fmaf(xD.x, mxv.x, fmaf(xD.y, mxv.y, mbv)); \
  Gq = __builtin_amdgcn_mfma_f32_16x16x32_f16(Af, Bfv, Cv, 0, 0, 0); }

  #pragma unroll 1
  for (int t = 0; t < T_STEPS; ++t) {
    // ---- PHASE 1: w0-7 fused op1+nonlin -> sH; w8-15 3a(t+1) -> sw ----
    if (w < 8) {
      const half8 Af = *(const half8*)(sz_ + (16*r + n16)*40 + quad*8);
      f32x4 G0, G1, G2, G3;
      if (t == 0) {  // one-time LDS path: Whh weights + t0 bias
        const half8 Bw0 = *(const half8*)(sgw + (16*(c    ) + n16)*40 + quad*8);
        const half8 Bw1 = *(const half8*)(sgw + (16*(2 + c) + n16)*40 + quad*8);
        const half8 Bw2 = *(const half8*)(sgw + (16*(4 + c) + n16)*40 + quad*8);
        const half8 Bw3 = *(const half8*)(sgw + (16*(6 + c) + n16)*40 + quad*8);
        const float4 u0 = sgmb[16*(c    ) + n16];
        const float4 u1 = sgmb[16*(2 + c) + n16];
        const float4 u2 = sgmb[16*(4 + c) + n16];
        const float4 u3 = sgmb[16*(6 + c) + n16];
        const float2 m0 = make_float2(u0.x, u0.y), m1 = make_float2(u1.x, u1.y);
        const float2 m2 = make_float2(u2.x, u2.y), m3 = make_float2(u3.x, u3.y);
        OP1R(G0, Bw0, m0, u0.z) OP1R(G1, Bw1, m1, u1.z)
        OP1R(G2, Bw2, m2, u2.z) OP1R(G3, Bw3, m3, u3.z)
      } else {       // steady state: all operands in registers
        OP1R(G0, Bc0, mxq0, mbn0) OP1R(G1, Bc1, mxq1, mbn1)
        OP1R(G2, Bc2, mxq2, mbn2) OP1R(G3, Bc3, mxq3, mbn3)
      }
      // LSTM nonlin in-register; gates pre-scaled: i,f,o by -log2e, g by 2log2e
      const int hh = 16*c + n16;
      #pragma unroll
      for (int reg = 0; reg < 4; ++reg) {
        const float si = __builtin_amdgcn_rcpf(1.0f + exp2_f(G0[reg]));
        const float sf = __builtin_amdgcn_rcpf(1.0f + exp2_f(G1[reg]));
        const float tg = 1.0f - 2.0f*__builtin_amdgcn_rcpf(1.0f + exp2_f(G2[reg]));
        const float so = __builtin_amdgcn_rcpf(1.0f + exp2_f(G3[reg]));
        const float cc = fmaf(sf, ccell[reg], si * tg);
        ccell[reg] = cc;
        sH[(16*r + 4*quad + reg)*40 + hh] = (_Float16)(so * tanh_f(cc));
      }
      // x prefetch t+1 (rides across lgkm-only barriers)
      const int tn2 = ((t < T_STEPS - 1) ? t + 1 : t) << 1;
      xA = *(const float2*)(xpre + tn2);
      xB = *(const float2*)(xpre + tn2 +  40);
      xC = *(const float2*)(xpre + tn2 +  80);
      xD = *(const float2*)(xpre + tn2 + 120);
    } else {
      // 3a for step t+1 from regs (edges t+1), into the other sw buffer
      const int tn = (t < T_STEPS - 1) ? t + 1 : t;
      _Float16* swn = ((t + 1) & 1) ? swB : swA;
      DO_3A(tn, swn);
      // edge prefetch t+2 (~full step of latency cover)
      const int tp = (t < T_STEPS - 2) ? t + 2 : T_STEPS - 1;
      const size_t eb2 = ebp + (size_t)tp*64;
      dmv0 = *(const f32x4*)(dmat + eb2); dmv1 = *(const f32x4*)(dmat + eb2 + 4);
      bmv0 = *(const f32x4*)(bmat + eb2); bmv1 = *(const f32x4*)(bmat + eb2 + 4);
      hmv0 = *(const f32x4*)(hmat + eb2); hmv1 = *(const f32x4*)(hmat + eb2 + 4);
    }
    barrier_lgkm();  // X: sH + sw[t&1] visible

    // ---- PHASE 2 (w0-7): P + own Q stripe + private transpose + op3 ----
    if (w < 8) {
      const _Float16* swr = (t & 1) ? swB : swA;
      _Float16* qb = sqb + w*(16*72);
      const half8 a0 = *(const half8*)(sH + (     n16)*40 + quad*8);
      const half8 a1 = *(const half8*)(sH + (16 + n16)*40 + quad*8);
      const half8 a2 = *(const half8*)(sH + (32 + n16)*40 + quad*8);
      const half8 a3 = *(const half8*)(sH + (48 + n16)*40 + quad*8);
      const half8 aP = *(const half8*)(sH + (16*r + n16)*40 + quad*8);
      const half8 A0 = *(const half8*)(swr + (16*r + n16)*72 + quad*8);
      const half8 A1 = *(const half8*)(swr + (16*r + n16)*72 + 32 + quad*8);
      f32x4 Pv; Pv[0] = bzv; Pv[1] = bzv; Pv[2] = bzv; Pv[3] = bzv;
      Pv = __builtin_amdgcn_mfma_f32_16x16x32_f16(aP, ESaB, Pv, 0, 0, 0);
      const f32x4 Z4 = {0.f, 0.f, 0.f, 0.f};
      const f32x4 D0 = __builtin_amdgcn_mfma_f32_16x16x32_f16(a0, EStB, Z4, 0, 0, 0);
      const f32x4 D1 = __builtin_amdgcn_mfma_f32_16x16x32_f16(a1, EStB, Z4, 0, 0, 0);
      const f32x4 D2 = __builtin_amdgcn_mfma_f32_16x16x32_f16(a2, EStB, Z4, 0, 0, 0);
      const f32x4 D3 = __builtin_amdgcn_mfma_f32_16x16x32_f16(a3, EStB, Z4, 0, 0, 0);
      *(int2*)(qb + n16*72 +  0 + 4*quad) = pkpair(D0);
      *(int2*)(qb + n16*72 + 16 + 4*quad) = pkpair(D1);
      *(int2*)(qb + n16*72 + 32 + 4*quad) = pkpair(D2);
      *(int2*)(qb + n16*72 + 48 + 4*quad) = pkpair(D3);
      const half8 Bf0 = *(const half8*)(qb + n16*72 + 8*quad);
      const half8 Bf1 = *(const half8*)(qb + n16*72 + 32 + 8*quad);
      Pv = __builtin_amdgcn_mfma_f32_16x16x32_f16(A0, Bf0, Pv, 0, 0, 0);
      Pv = __builtin_amdgcn_mfma_f32_16x16x32_f16(A1, Bf1, Pv, 0, 0, 0);
      const int nd = 16*r + 4*quad;
      sz_[(nd+0)*40 + 16*c + n16] = (_Float16)tanh_f(Pv[0]);
      sz_[(nd+1)*40 + 16*c + n16] = (_Float16)tanh_f(Pv[1]);
      sz_[(nd+2)*40 + 16*c + n16] = (_Float16)tanh_f(Pv[2]);
      sz_[(nd+3)*40 + 16*c + n16] = (_Float16)tanh_f(Pv[3]);
    }
    barrier_lgkm();  // Y: sz_ final; sw[t&1] reads drained before P1(t+1) rewrites
  }

#undef OP1R
#undef DO_3A
#undef WC

  // ---- classifier head (folded through a2e): out = sigm(tanh(z.clsc + b)) ----
  if (tid < 64) {
    float acc = sclsb2[0];
    #pragma unroll
    for (int k = 0; k < 32; ++k) acc = fmaf((float)sz_[tid*40 + k], sclsc[k], acc);
    out[(size_t)b*64 + tid] = sigm(tanh_f(acc));
  }
}

extern "C" void kernel_launch(void* const* d_in, const int* in_sizes, int n_in,
                              void* d_out, int out_size, void* d_ws, size_t ws_size,
                              hipStream_t stream) {
  (void)in_sizes; (void)n_in; (void)d_ws; (void)ws_size; (void)out_size;
  const float* x    = (const float*)d_in[0];
  const float* dmat = (const float*)d_in[1];
  const float* bmat = (const float*)d_in[2];
  const float* hmat = (const float*)d_in[3];
  const float* mask = (const float*)d_in[4];
  const float* embW = (const float*)d_in[5];
  const float* embb = (const float*)d_in[6];
  const float* Wih  = (const float*)d_in[7];
  const float* Whh  = (const float*)d_in[8];
  const float* bih  = (const float*)d_in[9];
  const float* bhh  = (const float*)d_in[10];
  const float* dom  = (const float*)d_in[11];
  const float* e2aW = (const float*)d_in[12];
  const float* e2ab = (const float*)d_in[13];
  const float* spaW = (const float*)d_in[14];
  const float* spab = (const float*)d_in[15];
  const float* a2eW = (const float*)d_in[16];
  const float* a2eb = (const float*)d_in[17];
  const float* clsW = (const float*)d_in[18];
  const float* clsb = (const float*)d_in[19];
  const float* h0   = (const float*)d_in[20];
  const float* c0   = (const float*)d_in[21];
  float* out = (float*)d_out;

  traj_disc<<<dim3(128), dim3(1024), 0, stream>>>(
      x, dmat, bmat, hmat, mask, embW, embb, Wih, Whh, bih, bhh, dom,
      e2aW, e2ab, spaW, spab, a2eW, a2eb, clsW, clsb, h0, c0, out);
}

// Round 11
// 203.123 us; speedup vs baseline: 1.3913x; 1.3913x over previous
//
#include <hip/hip_runtime.h>
#include <math.h>

#define T_STEPS 20
#define LOG2E 1.44269504088896f

typedef _Float16 half8 __attribute__((ext_vector_type(8)));
typedef _Float16 half4v __attribute__((ext_vector_type(4)));
typedef float f32x4 __attribute__((ext_vector_type(4)));

// native v_exp_f32 = 2^x (gate weights pre-scaled by +-log2e so no mul)
__device__ __forceinline__ float exp2_f(float v) {
  float r; asm("v_exp_f32 %0, %1" : "=v"(r) : "v"(v)); return r;
}
// helpers for cell tanh + classifier head (not prescaled)
__device__ __forceinline__ float sigm(float v) {
  return __builtin_amdgcn_rcpf(1.0f + __expf(-v));
}
__device__ __forceinline__ float tanh_f(float v) {
  return 1.0f - 2.0f * __builtin_amdgcn_rcpf(1.0f + __expf(2.0f * v));
}

// lgkm-only workgroup barrier (R1: neutral vs __syncthreads, never worse;
// lets global prefetch ride across barriers).
__device__ __forceinline__ void barrier_lgkm() {
  asm volatile("s_waitcnt lgkmcnt(0)" ::: "memory");
  __builtin_amdgcn_s_barrier();
  asm volatile("" ::: "memory");
}

// R14 = R8 (best measured: 67.0us, 3 barriers/step, split wave roles, VGPR 56,
// no spill) + register-free VALU cuts only. Lessons enforced:
//  - R9/R10: 2-barrier merge with same-wave LDS round trip = slight regression
//    -> keep R8's 3-barrier split (w8-15 produce Q in op2, w0-7 consume in op3).
//  - R12/R13: persistent-reg hoists beyond ~64 VGPRs spill to scratch
//    (53MB/dispatch HBM traffic, 2x dur) and launch_bounds(1024,4) does NOT
//    raise the cap -> NO new persistent registers in this version.
// Cuts applied (all register-neutral, R11/R12-verified):
//  - sm stored [t][n]: 3a mask row = 2x f32x4 + broadcast (was 9 scalar
//    stride-20 reads).
//  - trunc-cast bins, upper clamp only (bm,hm in [0,360) by construction).
//  - gate weights/biases pre-scaled by -log2e (i,f,o) / +2log2e (g) at
//    staging -> nonlin uses raw v_exp_f32. Exact algebra.
// Step: P1 {w0-7: op1(4 MFMA)+nonlin->sH | w8-15: 3a(t)->sw, prefetch t+1}
//       B2; op2 {w0-7: P=H@ESa+bz (regs) | w8-15: Q=H@ESt -> sQT}
//       B3; op3 {w0-7: Z=tanh(P + w@Q) -> sz_} Bend.
// MFMA layouts (verified m89 + R7): A[m=lane&15][k=quad*8+j] row-major
// [m][k]; B[k][n=lane&15] row-major [n][k]; D row=4*quad+reg, col=lane&15.
__global__ __launch_bounds__(1024)
void traj_disc(const float* __restrict__ x, const float* __restrict__ dmat,
               const float* __restrict__ bmat, const float* __restrict__ hmat,
               const float* __restrict__ maskp,
               const float* __restrict__ embW, const float* __restrict__ embb,
               const float* __restrict__ Wih, const float* __restrict__ Whh,
               const float* __restrict__ bih, const float* __restrict__ bhh,
               const float* __restrict__ dom,
               const float* __restrict__ e2aW, const float* __restrict__ e2ab,
               const float* __restrict__ spaW, const float* __restrict__ spab,
               const float* __restrict__ a2eW, const float* __restrict__ a2eb,
               const float* __restrict__ clsW, const float* __restrict__ clsb,
               const float* __restrict__ h0p, const float* __restrict__ c0p,
               float* __restrict__ out)
{
  // f16 pitches 40/72 halves (80/144 B: 16B-aligned, <=2-way banks).
  __shared__ __align__(16) _Float16 sgw[128*40];   // Whh*s_q        (t=0 path)
  __shared__ __align__(16) _Float16 sgwc[128*40];  // (Whh@a2eW)*s_q (t>0 path)
  __shared__ __align__(16) float4   sgmb[128];     // (M0,M1,b_t0,b_tn)*s_q
  __shared__ __align__(16) _Float16 sESaT[32*40];  // (e2aW^T@spaW_a)^T[zk][h]
  __shared__ __align__(16) _Float16 sEStT[32*40];  // (e2aW^T@spaW_t)^T[zk][h]
  __shared__ float bz[32];                          // folded z bias
  __shared__ float sdom[144];
  __shared__ float sm[1280];                        // mask[b] as [t][n]
  __shared__ float sclsc[32];                       // clsW@a2eW fold
  __shared__ float sclsb2[1];
  __shared__ __align__(16) _Float16 sH[64*40];     // h_lstm rows f16
  __shared__ __align__(16) _Float16 sw[64*72];     // normalized w[i][j] f16
  __shared__ __align__(16) _Float16 sz_[64*40];    // Z rows f16 (recurrent state; h0 at t=0)
  __shared__ __align__(16) _Float16 sQT[32*72];    // Q^T[zk][node] f16

  const int tid = threadIdx.x;
  const int b = blockIdx.x;
  const int w = tid >> 6;     // wave 0..15
  const int l = tid & 63;
  const int quad = l >> 4;
  const int n16 = l & 15;
  const int i8 = (tid >= 512) ? ((tid - 512) >> 3) : 0;  // 3a node (waves 8-15)
  const int s8 = tid & 7;                                 // 3a j-block

  // ---- one-time staging ----
  for (int idx = tid; idx < 4096; idx += 1024) {
    const int g = idx >> 5;
    const float sq = ((g >> 5) == 2) ? 2.0f*LOG2E : -LOG2E;
    sgw[g*40 + (idx & 31)] = (_Float16)(Whh[idx] * sq);
  }
  {  // Wcomb[g][k] = sum_h Whh[g][h]*a2eW[h][k], then *s_q
    const int g = tid >> 3, kb = (tid & 7) << 2;
    const float sq = ((g >> 5) == 2) ? 2.0f*LOG2E : -LOG2E;
    float a0 = 0.f, a1 = 0.f, a2 = 0.f, a3 = 0.f;
    #pragma unroll
    for (int h = 0; h < 32; ++h) {
      const float wv = Whh[g*32 + h];
      a0 = fmaf(wv, a2eW[h*32 + kb + 0], a0);
      a1 = fmaf(wv, a2eW[h*32 + kb + 1], a1);
      a2 = fmaf(wv, a2eW[h*32 + kb + 2], a2);
      a3 = fmaf(wv, a2eW[h*32 + kb + 3], a3);
    }
    sgwc[g*40 + kb + 0] = (_Float16)(a0*sq); sgwc[g*40 + kb + 1] = (_Float16)(a1*sq);
    sgwc[g*40 + kb + 2] = (_Float16)(a2*sq); sgwc[g*40 + kb + 3] = (_Float16)(a3*sq);
  }
  if (tid < 128) {  // x-projection fold + both bias variants, *s_q
    const float sq = ((tid >> 5) == 2) ? 2.0f*LOG2E : -LOG2E;
    float m0 = 0.f, m1 = 0.f, b0 = bih[tid] + bhh[tid];
    #pragma unroll
    for (int e = 0; e < 16; ++e) {
      float wv_ = Wih[tid*16 + e];
      m0 = fmaf(wv_, embW[2*e],   m0);
      m1 = fmaf(wv_, embW[2*e+1], m1);
      b0 = fmaf(wv_, embb[e],     b0);
    }
    float bn = b0;
    #pragma unroll
    for (int h = 0; h < 32; ++h) bn = fmaf(Whh[tid*32 + h], a2eb[h], bn);
    sgmb[tid] = make_float4(m0*sq, m1*sq, b0*sq, bn*sq);
  }
  {  // ESa^T / ESt^T: entry (zk = tid>>5, h = tid&31)
    const int zk = tid >> 5, hc = tid & 31;
    float sa_ = 0.f, st_ = 0.f;
    #pragma unroll
    for (int a = 0; a < 32; ++a) {
      const float ev = e2aW[a*32 + hc];
      sa_ = fmaf(spaW[zk*64 + a],      ev, sa_);
      st_ = fmaf(spaW[zk*64 + 32 + a], ev, st_);
    }
    sESaT[zk*40 + hc] = (_Float16)sa_;
    sEStT[zk*40 + hc] = (_Float16)st_;
  }
  if (tid < 32) {  // bz fold + classifier fold
    float acc = spab[tid];
    #pragma unroll
    for (int a = 0; a < 32; ++a)
      acc = fmaf(e2ab[a], spaW[tid*64 + a] + spaW[tid*64 + 32 + a], acc);
    bz[tid] = acc;
    float cc = 0.f;
    #pragma unroll
    for (int h = 0; h < 32; ++h) cc = fmaf(clsW[h], a2eW[h*32 + tid], cc);
    sclsc[tid] = cc;
  }
  if (tid == 0) {
    float cb = clsb[0];
    #pragma unroll
    for (int h = 0; h < 32; ++h) cb = fmaf(clsW[h], a2eb[h], cb);
    sclsb2[0] = cb;
  }
  if (tid < 144) sdom[tid] = dom[tid];
  // mask as [t][n] (conflict-free broadcast + vector reads in 3a)
  for (int idx = tid; idx < 1280; idx += 1024)
    sm[idx] = maskp[(size_t)b*1280 + (size_t)(idx & 63)*20 + (idx >> 6)];
  // h0 -> sz_ (t=0 op1 reads sz_; sH is written fresh every step in P1)
  for (int idx = tid; idx < 2048; idx += 1024) sz_[(idx >> 5)*40 + (idx & 31)] = (_Float16)h0p[(size_t)b*2048 + idx];

  // per-path persistent registers
  f32x4 ccell;
  float2 xA, xB, xC, xD;
  f32x4 dmv0, dmv1, bmv0, bmv1, hmv0, hmv1;
  const float* xpre = nullptr;
  size_t ebp = 0;
  const int r = w >> 1, c = w & 1;   // waves 0-7: tile (node-block r, col-block c)
  if (w < 8) {
    const int hh = 16*c + n16;
    #pragma unroll
    for (int reg = 0; reg < 4; ++reg)
      ccell[reg] = c0p[(size_t)b*2048 + (size_t)(16*r + 4*quad + reg)*32 + hh];
    xpre = x + (size_t)(b*64 + 16*r + 4*quad) * 40;
    xA = *(const float2*)(xpre +   0);
    xB = *(const float2*)(xpre +  40);
    xC = *(const float2*)(xpre +  80);
    xD = *(const float2*)(xpre + 120);
  } else {
    ebp = ((size_t)(b*64 + i8)*20)*64 + (size_t)(s8*8);   // edges t=0
    dmv0 = *(const f32x4*)(dmat + ebp); dmv1 = *(const f32x4*)(dmat + ebp + 4);
    bmv0 = *(const f32x4*)(bmat + ebp); bmv1 = *(const f32x4*)(bmat + ebp + 4);
    hmv0 = *(const f32x4*)(hmat + ebp); hmv1 = *(const f32x4*)(hmat + ebp + 4);
  }
  __syncthreads();

  // bins: bm,hm in [0,360) -> trunc == floor; upper clamp = rounding insurance
#define WC(dst, k, dmv, bmv, hmv, mrv, jof) { \
  int ib_ = (int)(bmv[k] * (1.0f/30.0f)); ib_ = ib_ > 11 ? 11 : ib_; \
  int ih_ = (int)(hmv[k] * (1.0f/30.0f)); ih_ = ih_ > 11 ? 11 : ih_; \
  float w_ = fmaxf(sdom[ib_*12 + ih_] - dmv[k], 0.0f) * (mi_ * mrv[k]); \
  w_ = (8*s8 + (jof) == i8) ? 0.0f : w_; dst[k] = w_; rs += w_; }

#define DO_3A(tn_) { \
  const int tloc = (tn_); \
  const float mi_ = sm[tloc*64 + i8]; \
  const f32x4 mr0 = *(const f32x4*)(sm + tloc*64 + 8*s8); \
  const f32x4 mr1 = *(const f32x4*)(sm + tloc*64 + 8*s8 + 4); \
  f32x4 wnA, wnB; float rs = 0.0f; \
  WC(wnA,0,dmv0,bmv0,hmv0,mr0,0) WC(wnA,1,dmv0,bmv0,hmv0,mr0,1) \
  WC(wnA,2,dmv0,bmv0,hmv0,mr0,2) WC(wnA,3,dmv0,bmv0,hmv0,mr0,3) \
  WC(wnB,0,dmv1,bmv1,hmv1,mr1,4) WC(wnB,1,dmv1,bmv1,hmv1,mr1,5) \
  WC(wnB,2,dmv1,bmv1,hmv1,mr1,6) WC(wnB,3,dmv1,bmv1,hmv1,mr1,7) \
  rs += __shfl_xor(rs, 1); rs += __shfl_xor(rs, 2); rs += __shfl_xor(rs, 4); \
  const float inv_ = __builtin_amdgcn_rcpf(rs + 1e-12f); \
  half8 hw; \
  hw[0] = (_Float16)(wnA[0]*inv_); hw[1] = (_Float16)(wnA[1]*inv_); \
  hw[2] = (_Float16)(wnA[2]*inv_); hw[3] = (_Float16)(wnA[3]*inv_); \
  hw[4] = (_Float16)(wnB[0]*inv_); hw[5] = (_Float16)(wnB[1]*inv_); \
  hw[6] = (_Float16)(wnB[2]*inv_); hw[7] = (_Float16)(wnB[3]*inv_); \
  *(half8*)(sw + i8*72 + s8*8) = hw; }

  #pragma unroll 1
  for (int t = 0; t < T_STEPS; ++t) {
    // ---- PHASE 1: w0-7 fused op1+nonlin -> sH; w8-15 3a(t) -> sw ----
    if (w < 8) {
      const _Float16* Bbase = (t == 0) ? sgw : sgwc;
      const half8 Af = *(const half8*)(sz_ + (16*r + n16)*40 + quad*8);
      f32x4 G0, G1, G2, G3;
#define OP1Q(Gq, q) { \
      const int c_ = 2*(q) + c; \
      const half8 Bf = *(const half8*)(Bbase + (16*c_ + n16)*40 + quad*8); \
      const float4 mb = sgmb[16*c_ + n16]; \
      const float bb = (t == 0) ? mb.z : mb.w; \
      f32x4 Cv; \
      Cv[0] = fmaf(xA.x, mb.x, fmaf(xA.y, mb.y, bb)); \
      Cv[1] = fmaf(xB.x, mb.x, fmaf(xB.y, mb.y, bb)); \
      Cv[2] = fmaf(xC.x, mb.x, fmaf(xC.y, mb.y, bb)); \
      Cv[3] = fmaf(xD.x, mb.x, fmaf(xD.y, mb.y, bb)); \
      Gq = __builtin_amdgcn_mfma_f32_16x16x32_f16(Af, Bf, Cv, 0, 0, 0); }
      OP1Q(G0, 0) OP1Q(G1, 1) OP1Q(G2, 2) OP1Q(G3, 3)
#undef OP1Q
      // LSTM nonlin in-register; gates pre-scaled: i,f,o by -log2e, g by 2log2e
      const int hh = 16*c + n16;
      #pragma unroll
      for (int reg = 0; reg < 4; ++reg) {
        const float si = __builtin_amdgcn_rcpf(1.0f + exp2_f(G0[reg]));
        const float sf = __builtin_amdgcn_rcpf(1.0f + exp2_f(G1[reg]));
        const float tg = 1.0f - 2.0f*__builtin_amdgcn_rcpf(1.0f + exp2_f(G2[reg]));
        const float so = __builtin_amdgcn_rcpf(1.0f + exp2_f(G3[reg]));
        const float cc = fmaf(sf, ccell[reg], si * tg);
        ccell[reg] = cc;
        sH[(16*r + 4*quad + reg)*40 + hh] = (_Float16)(so * tanh_f(cc));
      }
      // x prefetch t+1 (rides across lgkm-only barriers)
      const int tn2 = ((t < T_STEPS - 1) ? t + 1 : t) << 1;
      xA = *(const float2*)(xpre + tn2);
      xB = *(const float2*)(xpre + tn2 +  40);
      xC = *(const float2*)(xpre + tn2 +  80);
      xD = *(const float2*)(xpre + tn2 + 120);
    } else {
      // 3a for current step t from regs (edges t), into sw
      DO_3A(t);
      // edge prefetch t+1 (~full step of latency cover)
      const int tn = (t < T_STEPS - 1) ? t + 1 : t;
      const size_t eb2 = ebp + (size_t)tn*64;
      dmv0 = *(const f32x4*)(dmat + eb2); dmv1 = *(const f32x4*)(dmat + eb2 + 4);
      bmv0 = *(const f32x4*)(bmat + eb2); bmv1 = *(const f32x4*)(bmat + eb2 + 4);
      hmv0 = *(const f32x4*)(hmat + eb2); hmv1 = *(const f32x4*)(hmat + eb2 + 4);
    }
    barrier_lgkm();  // B2: h_lstm + w visible

    // ---- op2: waves 0-7 P = H@ESa + bz (REGISTERS); waves 8-15 Q -> sQT ----
    f32x4 Pv = {0.f, 0.f, 0.f, 0.f};
    if (w < 8) {
      const half8 Af = *(const half8*)(sH    + (16*r + n16)*40 + quad*8);
      const half8 Bf = *(const half8*)(sESaT + (16*c + n16)*40 + quad*8);
      const float bzv = bz[16*c + n16];
      Pv[0] = bzv; Pv[1] = bzv; Pv[2] = bzv; Pv[3] = bzv;
      Pv = __builtin_amdgcn_mfma_f32_16x16x32_f16(Af, Bf, Pv, 0, 0, 0);
    } else {
      const int w8 = w - 8, r8 = w8 >> 1, c8 = w8 & 1;
      const half8 Af = *(const half8*)(sH    + (16*r8 + n16)*40 + quad*8);
      const half8 Bf = *(const half8*)(sEStT + (16*c8 + n16)*40 + quad*8);
      f32x4 Cv = {0.f, 0.f, 0.f, 0.f};
      Cv = __builtin_amdgcn_mfma_f32_16x16x32_f16(Af, Bf, Cv, 0, 0, 0);
      half4v hq;
      hq[0] = (_Float16)Cv[0]; hq[1] = (_Float16)Cv[1];
      hq[2] = (_Float16)Cv[2]; hq[3] = (_Float16)Cv[3];
      *(half4v*)(sQT + (16*c8 + n16)*72 + 16*r8 + 4*quad) = hq;
    }
    barrier_lgkm();  // B3: Q^T visible (P rides in registers)

    // ---- op3: Z = tanh(Pv + Wn@Q) (waves 0-7, same tile as their P) ----
    if (w < 8) {
      const half8 A0 = *(const half8*)(sw  + (16*r + n16)*72 + quad*8);
      const half8 A1 = *(const half8*)(sw  + (16*r + n16)*72 + 32 + quad*8);
      const half8 B0 = *(const half8*)(sQT + (16*c + n16)*72 + quad*8);
      const half8 B1 = *(const half8*)(sQT + (16*c + n16)*72 + 32 + quad*8);
      Pv = __builtin_amdgcn_mfma_f32_16x16x32_f16(A0, B0, Pv, 0, 0, 0);
      Pv = __builtin_amdgcn_mfma_f32_16x16x32_f16(A1, B1, Pv, 0, 0, 0);
      const int nd = 16*r + 4*quad;
      sz_[(nd+0)*40 + 16*c + n16] = (_Float16)tanh_f(Pv[0]);
      sz_[(nd+1)*40 + 16*c + n16] = (_Float16)tanh_f(Pv[1]);
      sz_[(nd+2)*40 + 16*c + n16] = (_Float16)tanh_f(Pv[2]);
      sz_[(nd+3)*40 + 16*c + n16] = (_Float16)tanh_f(Pv[3]);
    }
    barrier_lgkm();  // Bend: Z final for this step (op1(t+1) reads it)
  }

#undef DO_3A
#undef WC

  // ---- classifier head (folded through a2e): out = sigm(tanh(z.clsc + b)) ----
  if (tid < 64) {
    float acc = sclsb2[0];
    #pragma unroll
    for (int k = 0; k < 32; ++k) acc = fmaf((float)sz_[tid*40 + k], sclsc[k], acc);
    out[(size_t)b*64 + tid] = sigm(tanh_f(acc));
  }
}

extern "C" void kernel_launch(void* const* d_in, const int* in_sizes, int n_in,
                              void* d_out, int out_size, void* d_ws, size_t ws_size,
                              hipStream_t stream) {
  (void)in_sizes; (void)n_in; (void)d_ws; (void)ws_size; (void)out_size;
  const float* x    = (const float*)d_in[0];
  const float* dmat = (const float*)d_in[1];
  const float* bmat = (const float*)d_in[2];
  const float* hmat = (const float*)d_in[3];
  const float* mask = (const float*)d_in[4];
  const float* embW = (const float*)d_in[5];
  const float* embb = (const float*)d_in[6];
  const float* Wih  = (const float*)d_in[7];
  const float* Whh  = (const float*)d_in[8];
  const float* bih  = (const float*)d_in[9];
  const float* bhh  = (const float*)d_in[10];
  const float* dom  = (const float*)d_in[11];
  const float* e2aW = (const float*)d_in[12];
  const float* e2ab = (const float*)d_in[13];
  const float* spaW = (const float*)d_in[14];
  const float* spab = (const float*)d_in[15];
  const float* a2eW = (const float*)d_in[16];
  const float* a2eb = (const float*)d_in[17];
  const float* clsW = (const float*)d_in[18];
  const float* clsb = (const float*)d_in[19];
  const float* h0   = (const float*)d_in[20];
  const float* c0   = (const float*)d_in[21];
  float* out = (float*)d_out;

  traj_disc<<<dim3(128), dim3(1024), 0, stream>>>(
      x, dmat, bmat, hmat, mask, embW, embb, Wih, Whh, bih, bhh, dom,
      e2aW, e2ab, spaW, spab, a2eW, a2eb, clsW, clsb, h0, c0, out);
}